// Round 1
// baseline (362.014 us; speedup 1.0000x reference)
//
#include <hip/hip_runtime.h>
#include <hip/hip_bf16.h>
#include <cstdint>

// Problem constants (fixed by the reference).
#define CDIM   256      // channels == code dim == K depth
#define NCODES 256
#define HWB    32768    // H*W = 128*256
#define BATCH  4
#define PX     64       // pixels per tile
#define TPB    512      // 8 waves per block
#define TILES  4        // pixel tiles per block (2048 tiles / 512 blocks)

typedef __bf16 bf16x8 __attribute__((ext_vector_type(8)));
typedef float  f32x4  __attribute__((ext_vector_type(4)));

// XOR swizzle: k-offset (units of bf16 elements, 8-aligned) by pixel row.
// Row stride is 256 bf16 = 512 B -> all rows alias bank-wise without this.
#define SW(k8, p) ((k8) ^ (((p) & 7) << 3))

// ---------------------------------------------------------------------------
// Kernel 1: inv_norm[n] = 1 / sum_c codebook[n][c]^2.  One wave per code row.
// ---------------------------------------------------------------------------
__global__ void norms_kernel(const float* __restrict__ cb, float* __restrict__ inv_norm) {
    const int n = blockIdx.x;
    const int lane = threadIdx.x;   // 64 threads
    const float* row = cb + n * CDIM;
    float s = 0.f;
#pragma unroll
    for (int c = 0; c < CDIM; c += 64) {
        float v = row[c + lane];
        s += v * v;
    }
#pragma unroll
    for (int off = 32; off > 0; off >>= 1) s += __shfl_down(s, off, 64);
    if (lane == 0) inv_norm[n] = 1.0f / s;
}

// ---------------------------------------------------------------------------
// Kernel 2: M[i][j] = sum_n cb[n][i] * inv_norm[n] * cb[n][j], stored bf16
// row-major [256][256].
// ---------------------------------------------------------------------------
__global__ void mmat_kernel(const float* __restrict__ cb, const float* __restrict__ inv_norm,
                            __bf16* __restrict__ Mb) {
    const int i = blockIdx.x;
    const int j = threadIdx.x;
    float acc = 0.f;
#pragma unroll 4
    for (int n = 0; n < NCODES; ++n) {
        acc += (cb[n * CDIM + i] * inv_norm[n]) * cb[n * CDIM + j];
    }
    Mb[i * CDIM + j] = (__bf16)acc;
}

// ---------------------------------------------------------------------------
// Kernel 3: out[b,c,p] = sum_k M[c][k] * feat[b,k,p].
//
// Restructured: M fragments live in REGISTERS (wave w owns rows w*32..w*32+31,
// full K=256 -> 64 VGPRs/lane, loaded once per block).  Each block processes
// TILES=4 pixel tiles of 64 px, streaming the feature through a double-
// buffered, XOR-swizzled LDS tile [64 px][256 k] bf16 (2 x 32 KB).
//
// Per tile: 4 sub-phases of { issue 8 prefetch dword loads for tile t+1 ->
// 16 MFMAs (2 K-chunks) on tile t -> cvt + swizzled ds_write }.  One barrier
// per tile; no loads in flight at the barrier, so the compiler's
// vmcnt(0)-before-s_barrier drain is free.
// ---------------------------------------------------------------------------
__global__ __launch_bounds__(TPB, 4) void recon_kernel(
    const float* __restrict__ feat, const __bf16* __restrict__ Mb,
    float* __restrict__ out) {
    __shared__ __align__(16) __bf16 Blds[2][PX * CDIM];   // 2 x 32 KB

    const int tid  = threadIdx.x;
    const int lane = tid & 63;
    const int w    = tid >> 6;       // wave 0..7
    const int quad = lane >> 4;      // 0..3
    const int l16  = lane & 15;
    const int r0   = w * 32;         // this wave's output-row base

    // ---- M fragments: A[row = r0+mt*16+l16][k = kc*32 + quad*8 + j] --------
    bf16x8 mreg[2][8];
#pragma unroll
    for (int mt = 0; mt < 2; ++mt)
#pragma unroll
        for (int kc = 0; kc < 8; ++kc)
            mreg[mt][kc] = *(const bf16x8*)(
                Mb + (size_t)(r0 + mt * 16 + l16) * CDIM + kc * 32 + quad * 8);

    f32x4 acc[2][4];
#pragma unroll
    for (int mt = 0; mt < 2; ++mt)
#pragma unroll
        for (int nt = 0; nt < 4; ++nt)
            acc[mt][nt] = (f32x4){0.f, 0.f, 0.f, 0.f};

    const int tile0 = blockIdx.x * TILES;

    // ---- Prologue: stage tile0 into buffer 0 -------------------------------
    {
        const int t  = tile0;
        const int b  = t >> 9;              // 512 tiles per batch image
        const int p0 = (t & 511) << 6;
        const float* fb = feat + (size_t)b * CDIM * HWB + p0 + lane;
#pragma unroll
        for (int sub = 0; sub < 4; ++sub) {
            const int k0 = sub * 64 + w * 8;
            float fv[8];
#pragma unroll
            for (int j = 0; j < 8; ++j) fv[j] = fb[(size_t)(k0 + j) * HWB];
            bf16x8 pk;
#pragma unroll
            for (int j = 0; j < 8; ++j) pk[j] = (__bf16)fv[j];
            *(bf16x8*)(&Blds[0][0] + lane * CDIM + SW(k0, lane)) = pk;
        }
    }
    __syncthreads();

    int cur = 0;
    for (int ti = 0; ti < TILES; ++ti) {
        const int t  = tile0 + ti;
        const int b  = t >> 9;
        const int p0 = (t & 511) << 6;
        const bool pf = (ti + 1 < TILES);
        const int tn = t + 1;
        const float* fbn = feat + (size_t)(tn >> 9) * CDIM * HWB
                                + ((tn & 511) << 6) + lane;
        const __bf16* ldsr = &Blds[cur][0];
        __bf16*       ldsw = &Blds[cur ^ 1][0];

#pragma unroll
        for (int sub = 0; sub < 4; ++sub) {
            const int k0 = sub * 64 + w * 8;
            // -- issue prefetch loads for tile t+1 (consumed after MFMAs) ----
            float fv[8];
            if (pf) {
#pragma unroll
                for (int j = 0; j < 8; ++j) fv[j] = fbn[(size_t)(k0 + j) * HWB];
            }
            // -- MFMA quarter: 2 K-chunks of 32 on the current tile ----------
#pragma unroll
            for (int kc2 = 0; kc2 < 2; ++kc2) {
                const int kc = sub * 2 + kc2;
                bf16x8 bfr[4];
#pragma unroll
                for (int nt = 0; nt < 4; ++nt) {
                    const int row = nt * 16 + l16;
                    bfr[nt] = *(const bf16x8*)(
                        ldsr + row * CDIM + SW(kc * 32 + quad * 8, row));
                }
#pragma unroll
                for (int mt = 0; mt < 2; ++mt)
#pragma unroll
                    for (int nt = 0; nt < 4; ++nt)
                        acc[mt][nt] = __builtin_amdgcn_mfma_f32_16x16x32_bf16(
                            mreg[mt][kc], bfr[nt], acc[mt][nt], 0, 0, 0);
            }
            // -- consume prefetch: cvt + swizzled transpose-write ------------
            if (pf) {
                bf16x8 pk;
#pragma unroll
                for (int j = 0; j < 8; ++j) pk[j] = (__bf16)fv[j];
                *(bf16x8*)(ldsw + lane * CDIM + SW(k0, lane)) = pk;
            }
        }

        // -- Epilogue for tile t: D[row = quad*4+r][col = l16] per 16x16 -----
        float* ob = out + (size_t)b * CDIM * HWB + p0 + l16;
#pragma unroll
        for (int mt = 0; mt < 2; ++mt)
#pragma unroll
            for (int r = 0; r < 4; ++r) {
                float* orow = ob + (size_t)(r0 + mt * 16 + quad * 4 + r) * HWB;
#pragma unroll
                for (int nt = 0; nt < 4; ++nt) orow[nt * 16] = acc[mt][nt][r];
            }
#pragma unroll
        for (int mt = 0; mt < 2; ++mt)
#pragma unroll
            for (int nt = 0; nt < 4; ++nt)
                acc[mt][nt] = (f32x4){0.f, 0.f, 0.f, 0.f};

        __syncthreads();   // buf[cur^1] fully written; all reads of buf[cur] done
        cur ^= 1;
    }
}

// ---------------------------------------------------------------------------
extern "C" void kernel_launch(void* const* d_in, const int* in_sizes, int n_in,
                              void* d_out, int out_size, void* d_ws, size_t ws_size,
                              hipStream_t stream) {
    const float* feat = (const float*)d_in[0];   // [4,256,128,256] fp32
    const float* cb   = (const float*)d_in[1];   // [256,256] fp32
    float* out = (float*)d_out;

    float*  inv_norm = (float*)d_ws;                       // 1 KB
    __bf16* Mb       = (__bf16*)((char*)d_ws + 1024);      // 128 KB bf16 M

    norms_kernel<<<NCODES, 64, 0, stream>>>(cb, inv_norm);
    mmat_kernel<<<NCODES, CDIM, 0, stream>>>(cb, inv_norm, Mb);

    const int nblocks = (HWB * BATCH) / (PX * TILES);      // 512
    recon_kernel<<<nblocks, TPB, 0, stream>>>(feat, Mb, out);
}

// Round 2
// 253.505 us; speedup vs baseline: 1.4280x; 1.4280x over previous
//
#include <hip/hip_runtime.h>
#include <hip/hip_bf16.h>
#include <cstdint>

// Problem constants (fixed by the reference).
#define CDIM   256      // channels == code dim
#define NCODES 256
#define HWB    32768    // H*W = 128*256
#define BATCH  4
#define BN     64       // pixels per block tile
#define BK     32       // K-chunk (one 16x16x32 MFMA deep)

typedef __bf16 bf16x8 __attribute__((ext_vector_type(8)));
typedef float  f32x4  __attribute__((ext_vector_type(4)));

// ---------------------------------------------------------------------------
// Fused prep: M[i][j] = sum_n (cb[n][i]/||cb_n||^2) * cb[n][j], bf16 out.
// One block per row i.  Phase 1: thread j computes ||cb_j||^2 (rows are
// L2-resident, 256 KB total) and s[j] = cb[j][i]/norm into LDS.  Phase 2:
// coalesced dot over n with LDS-broadcast s[n].
// ---------------------------------------------------------------------------
__global__ __launch_bounds__(256) void prep_kernel(const float* __restrict__ cb,
                                                   __bf16* __restrict__ Mb) {
    __shared__ float s[NCODES];
    const int i = blockIdx.x;
    const int j = threadIdx.x;

    const float* row = cb + (size_t)j * CDIM;
    float nrm = 0.f;
#pragma unroll 8
    for (int c = 0; c < CDIM; c += 4) {
        f32x4 v = *(const f32x4*)(row + c);
        nrm += v[0] * v[0] + v[1] * v[1] + v[2] * v[2] + v[3] * v[3];
    }
    s[j] = cb[(size_t)j * CDIM + i] / nrm;
    __syncthreads();

    float acc = 0.f;
#pragma unroll 16
    for (int n = 0; n < NCODES; ++n)
        acc += s[n] * cb[(size_t)n * CDIM + j];
    Mb[(size_t)i * CDIM + j] = (__bf16)acc;
}

// ---------------------------------------------------------------------------
// recon: out[b,c,p] = sum_k M[c][k] * feat[b,k,p].
// Block = 256 thr (4 waves), tile = 256(c) x 64(p), K-loop 8 chunks of 32.
// Minimum 2-phase pipeline: stage chunk kc+1 (A via global_load_lds with
// pre-swizzled SOURCE, B via reg loads issued before the MFMAs) while
// MFMA-ing chunk kc.  One barrier per K-step; loads are in flight across
// the whole compute phase so the vmcnt drain at the barrier is cheap.
//
// LDS granule swizzle (16B granules, 4 per 64B row): q_store = q ^ (row&3),
// applied identically on the A global source (rule: linear dest + inv-swz
// source + swz read) and on the B ds_write/ds_read pair.  This spreads every
// wave access over all 8 bank-groups (half-wave balanced) -> conflict-free.
// LDS = 2*16K (A) + 2*4K (B) = 40 KB -> exactly 4 blocks/CU at 160 KB.
// ---------------------------------------------------------------------------
__global__ __launch_bounds__(256, 4) void recon_kernel(
    const float* __restrict__ feat, const __bf16* __restrict__ Mb,
    float* __restrict__ out) {
    __shared__ __align__(16) __bf16 Alds[2][CDIM * BK];   // 2 x 16 KB
    __shared__ __align__(16) __bf16 Blds[2][BN * BK];     // 2 x 4 KB

    const int tid  = threadIdx.x;
    const int lane = tid & 63;
    const int w    = tid >> 6;       // wave 0..3
    const int quad = lane >> 4;      // 0..3
    const int l16  = lane & 15;

    const int b  = blockIdx.y;
    const int p0 = blockIdx.x * BN;

    const float* fbase = feat + ((size_t)b * CDIM) * HWB + p0;
    float*       obase = out  + ((size_t)b * CDIM) * HWB + p0;

    f32x4 acc[4][4];
#pragma unroll
    for (int mt = 0; mt < 4; ++mt)
#pragma unroll
        for (int nt = 0; nt < 4; ++nt)
            acc[mt][nt] = (f32x4){0.f, 0.f, 0.f, 0.f};

    // B staging: thread -> px = lane, k rows = w*8 + j.  Coalesced dwords.
    const float* fp0 = fbase + (size_t)(w * 8) * HWB + lane;
    // B write swizzle: k-granule w stored at q = w ^ (px&3) within px's row.
    const int bw_off = lane * BK + (w ^ (lane & 3)) * 8;
    // A staging: granule g = j*256 + w*64 + lane; dest row r = g>>2 (granule
    // index within row = g&3 = lane&3); source k-granule = (g&3) ^ (r&3).
    const int qsrcA = (lane & 3) ^ ((lane >> 2) & 3);   // per-lane constant
    // Read-side swizzled granule offsets (granule q=quad, row&3 = l16&3):
    const int qrd = (quad ^ (l16 & 3)) * 8;

    // ---- Prologue: stage chunk 0 into buffer 0 -----------------------------
    {
        float fv[8];
#pragma unroll
        for (int j = 0; j < 8; ++j) fv[j] = fp0[(size_t)j * HWB];
#pragma unroll
        for (int j = 0; j < 4; ++j) {
            const int gbase = j * 256 + (w << 6);
            const int r = (gbase + lane) >> 2;
            const __bf16* gsrc = Mb + (size_t)r * CDIM + qsrcA * 8;
            __builtin_amdgcn_global_load_lds(
                (const __attribute__((address_space(1))) void*)gsrc,
                (__attribute__((address_space(3))) void*)(&Alds[0][0] + (size_t)gbase * 8),
                16, 0, 0);
        }
        bf16x8 pk;
#pragma unroll
        for (int j = 0; j < 8; ++j) pk[j] = (__bf16)fv[j];
        *(bf16x8*)(&Blds[0][0] + bw_off) = pk;
    }
    __syncthreads();

    int cur = 0;
    for (int kc = 0; kc < 8; ++kc) {
        const bool pf = (kc + 1 < 8);
        // ---- STAGE chunk kc+1 into buf cur^1 (issued before compute) ------
        float fv[8];
        if (pf) {
            const float* fp = fp0 + (size_t)(kc + 1) * BK * HWB;
#pragma unroll
            for (int j = 0; j < 8; ++j) fv[j] = fp[(size_t)j * HWB];
#pragma unroll
            for (int j = 0; j < 4; ++j) {
                const int gbase = j * 256 + (w << 6);
                const int r = (gbase + lane) >> 2;
                const __bf16* gsrc = Mb + (size_t)r * CDIM + (kc + 1) * BK + qsrcA * 8;
                __builtin_amdgcn_global_load_lds(
                    (const __attribute__((address_space(1))) void*)gsrc,
                    (__attribute__((address_space(3))) void*)(&Alds[cur ^ 1][0] + (size_t)gbase * 8),
                    16, 0, 0);
            }
        }

        // ---- MFMA on buf cur ----------------------------------------------
        bf16x8 bfr[4];
#pragma unroll
        for (int nt = 0; nt < 4; ++nt)
            bfr[nt] = *(const bf16x8*)(&Blds[cur][0] + (nt * 16 + l16) * BK + qrd);
#pragma unroll
        for (int mt = 0; mt < 4; ++mt) {
            bf16x8 af = *(const bf16x8*)(&Alds[cur][0] + (w * 64 + mt * 16 + l16) * BK + qrd);
#pragma unroll
            for (int nt = 0; nt < 4; ++nt)
                acc[mt][nt] = __builtin_amdgcn_mfma_f32_16x16x32_bf16(
                    af, bfr[nt], acc[mt][nt], 0, 0, 0);
        }

        // ---- finish B stage: cvt + swizzled write (waits only on fv) ------
        if (pf) {
            bf16x8 pk;
#pragma unroll
            for (int j = 0; j < 8; ++j) pk[j] = (__bf16)fv[j];
            *(bf16x8*)(&Blds[cur ^ 1][0] + bw_off) = pk;
        }
        __syncthreads();   // next-chunk A gll drained; reads of cur done
        cur ^= 1;
    }

    // ---- Epilogue: D[row=quad*4+r][col=l16] per 16x16 tile -----------------
#pragma unroll
    for (int mt = 0; mt < 4; ++mt) {
#pragma unroll
        for (int r = 0; r < 4; ++r) {
            const int c = w * 64 + mt * 16 + quad * 4 + r;
            float* orow = obase + (size_t)c * HWB + l16;
#pragma unroll
            for (int nt = 0; nt < 4; ++nt)
                orow[nt * 16] = acc[mt][nt][r];
        }
    }
}

// ---------------------------------------------------------------------------
extern "C" void kernel_launch(void* const* d_in, const int* in_sizes, int n_in,
                              void* d_out, int out_size, void* d_ws, size_t ws_size,
                              hipStream_t stream) {
    const float* feat = (const float*)d_in[0];   // [4,256,128,256] fp32
    const float* cb   = (const float*)d_in[1];   // [256,256] fp32
    float* out = (float*)d_out;

    __bf16* Mb = (__bf16*)d_ws;                  // 128 KB bf16 M

    prep_kernel<<<NCODES, 256, 0, stream>>>(cb, Mb);

    dim3 grid(HWB / BN, BATCH);   // 512 x 4 blocks
    recon_kernel<<<grid, 256, 0, stream>>>(feat, Mb, out);
}